// Round 12
// baseline (587.696 us; speedup 1.0000x reference)
//
#include <hip/hip_runtime.h>
#include <hip/hip_bf16.h>

// ---------------- common types / helpers ----------------
typedef __attribute__((ext_vector_type(8))) short short8;   // 8 x bf16 bits (4 VGPRs)
typedef __attribute__((ext_vector_type(4))) float f32x4;
typedef __attribute__((ext_vector_type(16))) float f32x16;
typedef unsigned short ushort_t;

__device__ __forceinline__ unsigned short f2bf(float x) {
    unsigned int u = __builtin_bit_cast(unsigned int, x);
    unsigned int r = (u + 0x7fffu + ((u >> 16) & 1u)) >> 16;   // RNE
    return (unsigned short)r;
}

__device__ __forceinline__ void gload_lds16(const ushort_t* g, ushort_t* l) {
    __builtin_amdgcn_global_load_lds(
        (const __attribute__((address_space(1))) void*)g,
        (__attribute__((address_space(3))) void*)l, 16, 0, 0);
}

#define MFMA16(A, B, C) __builtin_amdgcn_mfma_f32_16x16x32_bf16((A), (B), (C), 0, 0, 0)
#define MFMA32(A, B, C) __builtin_amdgcn_mfma_f32_32x32x16_bf16((A), (B), (C), 0, 0, 0)

// ---------------- fused prep: fp32->bf16 convert (5 tensors) + sincos table ----------------
__global__ __launch_bounds__(256) void prep_all(const float* __restrict__ im,
                                                const float* __restrict__ iq,
                                                const float* __restrict__ ik,
                                                const float* __restrict__ iv,
                                                const float* __restrict__ io,
                                                ushort_t* __restrict__ om,
                                                ushort_t* __restrict__ oq,
                                                ushort_t* __restrict__ ok,
                                                ushort_t* __restrict__ ov,
                                                ushort_t* __restrict__ oo,
                                                ushort_t* __restrict__ qh) {
    const int bid = blockIdx.x;
    if (bid < 14336) {
        long i = ((long)bid * 256 + threadIdx.x) << 3;
        const float* s;
        ushort_t* d;
        if (i < 16777216)      { s = im + i;              d = om + i; }
        else if (i < 20971520) { s = iq + (i - 16777216); d = oq + (i - 16777216); }
        else if (i < 23068672) { s = ik + (i - 20971520); d = ok + (i - 20971520); }
        else if (i < 25165824) { s = iv + (i - 23068672); d = ov + (i - 23068672); }
        else                   { s = io + (i - 25165824); d = oo + (i - 25165824); }
        const float4* p = (const float4*)s;
        float4 a = p[0], b = p[1];
        short8 o;
        o[0] = (short)f2bf(a.x); o[1] = (short)f2bf(a.y);
        o[2] = (short)f2bf(a.z); o[3] = (short)f2bf(a.w);
        o[4] = (short)f2bf(b.x); o[5] = (short)f2bf(b.y);
        o[6] = (short)f2bf(b.z); o[7] = (short)f2bf(b.w);
        *(short8*)d = o;
    } else {
        int idx = (bid - 14336) * 256 + threadIdx.x;   // over 2048*1024
        int e = idx >> 10, i = idx & 1023;
        float freq = __expf(-9.2103403719761836f * (float)i * (1.0f / 1024.0f));
        float ang = (float)e * freq;
        float rev = ang * 0.15915494309189535f;
        rev -= floorf(rev);
        float sv, cv;
        asm("v_sin_f32 %0, %1" : "=v"(sv) : "v"(rev));
        asm("v_cos_f32 %0, %1" : "=v"(cv) : "v"(rev));
        qh[(size_t)e * 2048 + i]        = f2bf(sv);
        qh[(size_t)e * 2048 + 1024 + i] = f2bf(cv);
    }
}

// ---------------- Q-proj GEMM: 128x128, BK=32, QUAD-buffer, counted vmcnt ----------
__global__ __launch_bounds__(256, 2) void gemm_q(const ushort_t* __restrict__ A,
                                                 const ushort_t* __restrict__ Bw,
                                                 const float* __restrict__ bias,
                                                 ushort_t* __restrict__ Cout,
                                                 int M, int N, int K) {
    __shared__ ushort_t As[4][128 * 32];
    __shared__ ushort_t Bs[4][128 * 32];
    const int tid = threadIdx.x, lane = tid & 63;
    const int wid = tid >> 6;
    const int q5 = lane & 31, hi = lane >> 5;
    const int wm = wid >> 1, wn = wid & 1;
    const int nbn = N >> 7;
    const int nwg = gridDim.x;
    const int swz = (blockIdx.x & 7) * (nwg >> 3) + (blockIdx.x >> 3);
    const int bm = swz / nbn, bn = swz % nbn;
    const int row0 = bm << 7, col0 = bn << 7;
    const int NT = K >> 5;

    f32x16 acc[2][2];
#pragma unroll
    for (int mi = 0; mi < 2; ++mi)
#pragma unroll
        for (int nj = 0; nj < 2; ++nj)
#pragma unroll
            for (int rr = 0; rr < 16; ++rr) acc[mi][nj][rr] = 0.f;

    auto STAGE_HALF = [&](int buf, int kt, int i) {
        const int k0 = kt << 5;
        const int fb = (i * 256 + tid) << 4;
        const int rp = fb >> 7;
        const int bo = ((fb >> 4) & 7) ^ (rp & 7);
        const int row = rp * 2 + (bo >> 2);
        const int kc = (bo & 3) << 3;
        gload_lds16(A  + (size_t)(row0 + row) * K + k0 + kc, &As[buf][0] + (fb >> 1));
        gload_lds16(Bw + (size_t)(col0 + row) * K + k0 + kc, &Bs[buf][0] + (fb >> 1));
    };

    STAGE_HALF(0, 0, 0); STAGE_HALF(0, 0, 1);
    STAGE_HALF(1, 1, 0); STAGE_HALF(1, 1, 1);
    STAGE_HALF(2, 2, 0); STAGE_HALF(2, 2, 1);
    asm volatile("s_waitcnt vmcnt(8)" ::: "memory");
    __builtin_amdgcn_sched_barrier(0);
    __builtin_amdgcn_s_barrier();
    __builtin_amdgcn_sched_barrier(0);

    for (int t = 0; t < NT; ++t) {
        const int buf = t & 3;
        const char* Ab = (const char*)&As[buf][0];
        const char* Bb = (const char*)&Bs[buf][0];
#pragma unroll
        for (int ph = 0; ph < 2; ++ph) {
            short8 af[2], bfr[2];
#pragma unroll
            for (int nj = 0; nj < 2; ++nj) {
                const int col = wn * 64 + nj * 32 + q5;
                const int rp = col >> 1;
                const int blk = (((col & 1) << 2) + ph * 2 + hi) ^ (rp & 7);
                bfr[nj] = *(const short8*)(Bb + rp * 128 + blk * 16);
            }
#pragma unroll
            for (int mi = 0; mi < 2; ++mi) {
                const int row = wm * 64 + mi * 32 + q5;
                const int rp = row >> 1;
                const int blk = (((row & 1) << 2) + ph * 2 + hi) ^ (rp & 7);
                af[mi] = *(const short8*)(Ab + rp * 128 + blk * 16);
            }
            if (t + 3 < NT) STAGE_HALF((t + 3) & 3, t + 3, ph);
            __builtin_amdgcn_s_setprio(1);
#pragma unroll
            for (int mi = 0; mi < 2; ++mi)
#pragma unroll
                for (int nj = 0; nj < 2; ++nj)
                    acc[mi][nj] = MFMA32(af[mi], bfr[nj], acc[mi][nj]);
            __builtin_amdgcn_s_setprio(0);
        }

        if (t + 3 < NT) {
            asm volatile("s_waitcnt vmcnt(8)" ::: "memory");
        } else if (t + 2 < NT) {
            asm volatile("s_waitcnt vmcnt(4)" ::: "memory");
        } else if (t + 1 < NT) {
            asm volatile("s_waitcnt vmcnt(0)" ::: "memory");
        }
        if (t + 1 < NT) {
            __builtin_amdgcn_sched_barrier(0);
            __builtin_amdgcn_s_barrier();
            __builtin_amdgcn_sched_barrier(0);
        }
    }

#pragma unroll
    for (int mi = 0; mi < 2; ++mi)
#pragma unroll
        for (int nj = 0; nj < 2; ++nj) {
            const int col = col0 + wn * 64 + nj * 32 + q5;
            const float bv = bias[col];
#pragma unroll
            for (int rr = 0; rr < 16; ++rr) {
                const int row = row0 + wm * 64 + mi * 32 + (rr & 3) + 8 * (rr >> 2) + 4 * hi;
                Cout[(size_t)row * N + col] = f2bf((acc[mi][nj][rr] + bv) * 0.5f);
            }
        }
}

// ---------------- 256x256 GEMM, BK=32, QUAD-buffer, counted vmcnt(8), phase-split ----
// (proven round-10 version, unchanged)
template <int EPI>
__global__ __launch_bounds__(512, 1) void gemm256(const ushort_t* __restrict__ A,
                                                  const ushort_t* __restrict__ Bw,
                                                  const float* __restrict__ b0,
                                                  const float* __restrict__ b1,
                                                  void* __restrict__ C0,
                                                  void* __restrict__ C1,
                                                  int M, int N, int K) {
    __shared__ ushort_t As[4][256 * 32];
    __shared__ ushort_t Bs[4][256 * 32];
    const int tid = threadIdx.x, lane = tid & 63;
    const int wid = tid >> 6;
    const int q5 = lane & 31, hi = lane >> 5;
    const int wm = wid >> 2, wn = wid & 3;
    const int nbn = N >> 8;
    const int nwg = gridDim.x;
    const int swz = (blockIdx.x & 7) * (nwg >> 3) + (blockIdx.x >> 3);
    const int bm = swz / nbn, bn = swz % nbn;
    const int row0 = bm << 8, col0 = bn << 8;
    const int NT = K >> 5;

    f32x16 acc[4][2];
#pragma unroll
    for (int mi = 0; mi < 4; ++mi)
#pragma unroll
        for (int nj = 0; nj < 2; ++nj)
#pragma unroll
            for (int rr = 0; rr < 16; ++rr) acc[mi][nj][rr] = 0.f;

    auto STAGE_HALF = [&](int buf, int kt, int i) {
        const int k0 = kt << 5;
        const int fb = (i * 512 + tid) << 4;
        const int rp = fb >> 7;
        const int bo = ((fb >> 4) & 7) ^ (rp & 7);
        const int row = rp * 2 + (bo >> 2);
        const int kc = (bo & 3) << 3;
        gload_lds16(A  + (size_t)(row0 + row) * K + k0 + kc, &As[buf][0] + (fb >> 1));
        gload_lds16(Bw + (size_t)(col0 + row) * K + k0 + kc, &Bs[buf][0] + (fb >> 1));
    };

    STAGE_HALF(0, 0, 0); STAGE_HALF(0, 0, 1);
    STAGE_HALF(1, 1, 0); STAGE_HALF(1, 1, 1);
    STAGE_HALF(2, 2, 0); STAGE_HALF(2, 2, 1);
    asm volatile("s_waitcnt vmcnt(8)" ::: "memory");
    __builtin_amdgcn_sched_barrier(0);
    __builtin_amdgcn_s_barrier();
    __builtin_amdgcn_sched_barrier(0);

    for (int t = 0; t < NT; ++t) {
        const int buf = t & 3;
        const char* Ab = (const char*)&As[buf][0];
        const char* Bb = (const char*)&Bs[buf][0];
#pragma unroll
        for (int ph = 0; ph < 2; ++ph) {
            short8 af[4], bfr[2];
#pragma unroll
            for (int nj = 0; nj < 2; ++nj) {
                const int col = wn * 64 + nj * 32 + q5;
                const int rp = col >> 1;
                const int blk = (((col & 1) << 2) + ph * 2 + hi) ^ (rp & 7);
                bfr[nj] = *(const short8*)(Bb + rp * 128 + blk * 16);
            }
#pragma unroll
            for (int mi = 0; mi < 4; ++mi) {
                const int row = wm * 128 + mi * 32 + q5;
                const int rp = row >> 1;
                const int blk = (((row & 1) << 2) + ph * 2 + hi) ^ (rp & 7);
                af[mi] = *(const short8*)(Ab + rp * 128 + blk * 16);
            }
            if (t + 3 < NT) STAGE_HALF((t + 3) & 3, t + 3, ph);
            __builtin_amdgcn_s_setprio(1);
#pragma unroll
            for (int mi = 0; mi < 4; ++mi)
#pragma unroll
                for (int nj = 0; nj < 2; ++nj)
                    acc[mi][nj] = MFMA32(af[mi], bfr[nj], acc[mi][nj]);
            __builtin_amdgcn_s_setprio(0);
        }

        if (t + 3 < NT) {
            asm volatile("s_waitcnt vmcnt(8)" ::: "memory");
        } else if (t + 2 < NT) {
            asm volatile("s_waitcnt vmcnt(4)" ::: "memory");
        } else if (t + 1 < NT) {
            asm volatile("s_waitcnt vmcnt(0)" ::: "memory");
        }
        if (t + 1 < NT) {
            __builtin_amdgcn_sched_barrier(0);
            __builtin_amdgcn_s_barrier();
            __builtin_amdgcn_sched_barrier(0);
        }
    }

#pragma unroll
    for (int mi = 0; mi < 4; ++mi)
#pragma unroll
        for (int nj = 0; nj < 2; ++nj) {
            const int col = col0 + wn * 64 + nj * 32 + q5;
            if (EPI == 2) {
                float* outp = (float*)C0;
#pragma unroll
                for (int rr = 0; rr < 16; ++rr) {
                    const int row = row0 + wm * 128 + mi * 32 + (rr & 3) + 8 * (rr >> 2) + 4 * hi;
                    outp[(size_t)row * N + col] = acc[mi][nj][rr];
                }
            } else {
                if (col < 1024) {
                    const float bv = b0[col];
                    ushort_t* Kp = (ushort_t*)C0;
#pragma unroll
                    for (int rr = 0; rr < 16; ++rr) {
                        const int row = row0 + wm * 128 + mi * 32 + (rr & 3) + 8 * (rr >> 2) + 4 * hi;
                        Kp[(size_t)row * 1024 + col] = f2bf(acc[mi][nj][rr] + bv);
                    }
                } else {
                    const int vcol = col - 1024;
                    const float bv = b1[vcol];
                    ushort_t* Vt = (ushort_t*)C1;
#pragma unroll
                    for (int G = 0; G < 4; ++G) {
                        const int m0 = row0 + wm * 128 + mi * 32 + G * 8 + 4 * hi;
                        const int bb = m0 >> 11;
                        const int mm = m0 & 2047;
                        const size_t vtrow = (size_t)(bb * 8 + (vcol >> 7)) * 128 + (vcol & 127);
                        unsigned int p0 = (unsigned int)f2bf(acc[mi][nj][G * 4 + 0] + bv)
                                        | ((unsigned int)f2bf(acc[mi][nj][G * 4 + 1] + bv) << 16);
                        unsigned int p1 = (unsigned int)f2bf(acc[mi][nj][G * 4 + 2] + bv)
                                        | ((unsigned int)f2bf(acc[mi][nj][G * 4 + 3] + bv) << 16);
                        uint2 pk; pk.x = p0; pk.y = p1;
                        *(uint2*)(Vt + vtrow * 2048 + mm) = pk;
                    }
                }
            }
        }
}

// ---------------- GQA flash attention v6: 4 waves x 64 q-rows (2 q-groups) ----------
// Each K/V LDS fragment read now feeds 2 MFMAs (one per q-group) -> LDS reads per
// MFMA halved vs v5. h2 (key-half) sub-passes bound live registers.
// Q [2048, 16*128] (pre-scaled 0.5), K [8192, 1024], Vt [(b*8+kvh)*128+d][2048].
__global__ __launch_bounds__(256, 2) void attn_kernel(const ushort_t* __restrict__ Q,
                                                      const ushort_t* __restrict__ Kg,
                                                      const ushort_t* __restrict__ Vt,
                                                      ushort_t* __restrict__ O) {
    __shared__ ushort_t Ks[2][64 * 128];    // 16KB per buf
    __shared__ ushort_t Vts[2][128 * 64];   // 16KB per buf

    const int tid = threadIdx.x, lane = tid & 63, wid = tid >> 6;  // wid 0..3
    const int q5 = lane & 31;
    const int hi = lane >> 5;
    const int wg = (blockIdx.x & 7) * 64 + (blockIdx.x >> 3);
    const int bh = wg >> 3;          // 0..63 (b*16+h)
    const int chunk = wg & 7;        // 0..7: 256-row q-chunk
    const int b = bh >> 4, h = bh & 15, kvh = h >> 1;
    const int e0 = chunk * 256 + wid * 64;   // this wave's 64 q-rows

    short8 Qf[2][8];
#pragma unroll
    for (int qg = 0; qg < 2; ++qg) {
        const ushort_t* qp = Q + (size_t)(e0 + qg * 32 + q5) * 2048 + h * 128 + hi * 8;
#pragma unroll
        for (int c = 0; c < 8; ++c) Qf[qg][c] = *(const short8*)(qp + c * 16);
    }

    // per-lane LDS byte offsets; aK is h2-invariant (key&7 == q5&7), h2 adds 8192B
    unsigned aK[8];
#pragma unroll
    for (int c = 0; c < 8; ++c)
        aK[c] = q5 * 256 + (((c * 2 + hi) ^ (q5 & 7)) << 4);
    unsigned aV[4];
#pragma unroll
    for (int c16 = 0; c16 < 4; ++c16)
        aV[c16] = q5 * 128 + (((c16 * 2 + hi) ^ (q5 & 7)) << 4);

    float lrow[2] = {0.f, 0.f};
    f32x16 oacc[2][4];
#pragma unroll
    for (int qg = 0; qg < 2; ++qg)
#pragma unroll
        for (int d0 = 0; d0 < 4; ++d0)
#pragma unroll
            for (int r = 0; r < 16; ++r) oacc[qg][d0][r] = 0.f;

    const ushort_t* Kbase  = Kg + (size_t)b * 2048 * 1024 + kvh * 128;
    const ushort_t* Vtbase = Vt + (size_t)(b * 8 + kvh) * 128 * 2048;

    auto STAGE = [&](int buf, int kv0) {
#pragma unroll
        for (int i = 0; i < 4; ++i) {
            const int fb = (i * 4 + wid) * 1024 + lane * 16;
            const int key = fb >> 8;
            const int blk = (fb >> 4) & 15;
            gload_lds16(Kbase + (size_t)(kv0 + key) * 1024 + ((blk ^ (key & 7)) << 3),
                        &Ks[buf][0] + (fb >> 1));
            const int d = fb >> 7;
            const int kb = (fb >> 4) & 7;
            gload_lds16(Vtbase + (size_t)d * 2048 + kv0 + ((kb ^ (d & 7)) << 3),
                        &Vts[buf][0] + (fb >> 1));
        }
    };

    auto TILE = [&](int bo) {    // bo: 0 or 16384 (compile-time at call sites)
#pragma unroll
        for (int h2 = 0; h2 < 2; ++h2) {
            // ---- QK for 32 keys (this half), both q-groups share each ka read ----
            f32x16 s0, s1;
#pragma unroll
            for (int r = 0; r < 16; ++r) { s0[r] = 0.f; s1[r] = 0.f; }
            __builtin_amdgcn_s_setprio(1);
#pragma unroll
            for (int c = 0; c < 8; ++c) {
                short8 ka = *(const short8*)((const char*)Ks + bo + h2 * 8192 + aK[c]);
                s0 = MFMA32(ka, Qf[0][c], s0);
                s1 = MFMA32(ka, Qf[1][c], s1);
            }
            __builtin_amdgcn_s_setprio(0);

            // ---- unnormalized softmax ----
#pragma unroll
            for (int r = 0; r < 16; ++r) { s0[r] = __expf(s0[r]); s1[r] = __expf(s1[r]); }
            {
                float ta[8], tb[8];
#pragma unroll
                for (int i = 0; i < 8; ++i) { ta[i] = s0[2 * i] + s0[2 * i + 1];
                                              tb[i] = s1[2 * i] + s1[2 * i + 1]; }
#pragma unroll
                for (int s = 4; s > 0; s >>= 1)
#pragma unroll
                    for (int i = 0; i < s; ++i) { ta[i] += ta[i + s]; tb[i] += tb[i + s]; }
                lrow[0] += ta[0] + __shfl_xor(ta[0], 32);
                lrow[1] += tb[0] + __shfl_xor(tb[0], 32);
            }

            // ---- PV for this half's keys: c16 in {2*h2, 2*h2+1} ----
#pragma unroll
            for (int cc = 0; cc < 2; ++cc) {
                const int c16 = h2 * 2 + cc;
                const int q4a = cc * 2, q4b = cc * 2 + 1;
                union { unsigned int w[4]; short8 v; } pa0, pa1;
                {
                    unsigned int w0a, w0b, w1a, w1b;
                    asm("v_cvt_pk_bf16_f32 %0, %1, %2" : "=v"(w0a) : "v"(s0[q4a * 4 + 0]), "v"(s0[q4a * 4 + 1]));
                    asm("v_cvt_pk_bf16_f32 %0, %1, %2" : "=v"(w0b) : "v"(s0[q4a * 4 + 2]), "v"(s0[q4a * 4 + 3]));
                    asm("v_cvt_pk_bf16_f32 %0, %1, %2" : "=v"(w1a) : "v"(s0[q4b * 4 + 0]), "v"(s0[q4b * 4 + 1]));
                    asm("v_cvt_pk_bf16_f32 %0, %1, %2" : "=v"(w1b) : "v"(s0[q4b * 4 + 2]), "v"(s0[q4b * 4 + 3]));
                    auto r0 = __builtin_amdgcn_permlane32_swap(w0a, w1a, false, false);
                    auto r1 = __builtin_amdgcn_permlane32_swap(w0b, w1b, false, false);
                    pa0.w[0] = r0[0]; pa0.w[1] = r1[0]; pa0.w[2] = r0[1]; pa0.w[3] = r1[1];
                }
                {
                    unsigned int w0a, w0b, w1a, w1b;
                    asm("v_cvt_pk_bf16_f32 %0, %1, %2" : "=v"(w0a) : "v"(s1[q4a * 4 + 0]), "v"(s1[q4a * 4 + 1]));
                    asm("v_cvt_pk_bf16_f32 %0, %1, %2" : "=v"(w0b) : "v"(s1[q4a * 4 + 2]), "v"(s1[q4a * 4 + 3]));
                    asm("v_cvt_pk_bf16_f32 %0, %1, %2" : "=v"(w1a) : "v"(s1[q4b * 4 + 0]), "v"(s1[q4b * 4 + 1]));
                    asm("v_cvt_pk_bf16_f32 %0, %1, %2" : "=v"(w1b) : "v"(s1[q4b * 4 + 2]), "v"(s1[q4b * 4 + 3]));
                    auto r0 = __builtin_amdgcn_permlane32_swap(w0a, w1a, false, false);
                    auto r1 = __builtin_amdgcn_permlane32_swap(w0b, w1b, false, false);
                    pa1.w[0] = r0[0]; pa1.w[1] = r1[0]; pa1.w[2] = r0[1]; pa1.w[3] = r1[1];
                }
                __builtin_amdgcn_s_setprio(1);
#pragma unroll
                for (int d0 = 0; d0 < 4; ++d0) {
                    short8 vb = *(const short8*)((const char*)Vts + bo + aV[c16] + d0 * 4096);
                    oacc[0][d0] = MFMA32(pa0.v, vb, oacc[0][d0]);
                    oacc[1][d0] = MFMA32(pa1.v, vb, oacc[1][d0]);
                }
                __builtin_amdgcn_s_setprio(0);
            }
        }
    };

    STAGE(0, 0);
    __syncthreads();

#pragma unroll 1
    for (int tt = 0; tt < 16; ++tt) {
        STAGE(1, (2 * tt + 1) * 64);      // prefetch odd tile -> buf1
        TILE(0);                          // compute even tile from buf0
        __syncthreads();
        if (tt < 15) STAGE(0, (2 * tt + 2) * 64);  // prefetch next even -> buf0
        TILE(16384);                      // compute odd tile from buf1
        __syncthreads();
    }

    // ---- epilogue ----
#pragma unroll
    for (int qg = 0; qg < 2; ++qg)
#pragma unroll
        for (int reg = 0; reg < 16; ++reg) {
            const int qr = (reg & 3) + 8 * (reg >> 2) + 4 * hi;
            const float lr = __shfl(lrow[qg], qr);
            const float inv = 1.0f / lr;
            const int e = e0 + qg * 32 + qr;
            ushort_t* op = O + ((size_t)b * 2048 + e) * 2048 + h * 128 + q5;
#pragma unroll
            for (int d0 = 0; d0 < 4; ++d0)
                op[d0 * 32] = f2bf(oacc[qg][d0][reg] * inv);
        }
}

// ---------------- launch ----------------
extern "C" void kernel_launch(void* const* d_in, const int* in_sizes, int n_in,
                              void* d_out, int out_size, void* d_ws, size_t ws_size,
                              hipStream_t stream) {
    const float* mem_act = (const float*)d_in[0];
    const float* Wq = (const float*)d_in[1];
    const float* bq = (const float*)d_in[2];
    const float* Wk = (const float*)d_in[3];
    const float* bk = (const float*)d_in[4];
    const float* Wv = (const float*)d_in[5];
    const float* bv = (const float*)d_in[6];
    const float* Wo = (const float*)d_in[7];
    float* out = (float*)d_out;

    char* w = (char*)d_ws;
    ushort_t* memb = (ushort_t*)w; w += (size_t)16777216 * 2;  // [8192, 2048]
    ushort_t* wqb  = (ushort_t*)w; w += (size_t)4194304 * 2;   // [2048, 2048]
    ushort_t* wkvb = (ushort_t*)w; w += (size_t)4194304 * 2;   // [2048, 2048] = Wk | Wv
    ushort_t* wob  = (ushort_t*)w; w += (size_t)4194304 * 2;   // [2048, 2048]
    ushort_t* qh   = (ushort_t*)w; w += (size_t)4194304 * 2;   // [2048, 2048]
    ushort_t* Qp   = (ushort_t*)w; w += (size_t)4194304 * 2;   // [2048, 2048] (scaled by 0.5)
    ushort_t* Kp   = (ushort_t*)w; w += (size_t)8388608 * 2;   // [8192, 1024]
    ushort_t* Vtp  = (ushort_t*)w; w += (size_t)8388608 * 2;   // [4096, 2048] transposed V
    ushort_t* AO   = (ushort_t*)w; w += (size_t)16777216 * 2;  // [8192, 2048]

    dim3 blk(256);
    prep_all<<<22528, blk, 0, stream>>>(mem_act, Wq, Wk, Wv, Wo,
                                        memb, wqb, wkvb, wkvb + (size_t)2097152, wob, qh);

    gemm_q<<<16 * 16, blk, 0, stream>>>(qh, wqb, bq, Qp, 2048, 2048, 2048);

    // merged K+V projection: N=2048 (cols 0-1023 -> K, 1024-2047 -> V transposed)
    gemm256<0><<<256, dim3(512), 0, stream>>>(memb, wkvb, bk, bv, Kp, Vtp, 8192, 2048, 2048);

    attn_kernel<<<512, blk, 0, stream>>>(Qp, Kp, Vtp, AO);

    gemm256<2><<<256, dim3(512), 0, stream>>>(AO, wob, nullptr, nullptr, out, nullptr, 8192, 2048, 2048);
}

// Round 13
// 363.863 us; speedup vs baseline: 1.6152x; 1.6152x over previous
//
#include <hip/hip_runtime.h>
#include <hip/hip_bf16.h>

// ---------------- common types / helpers ----------------
typedef __attribute__((ext_vector_type(8))) short short8;   // 8 x bf16 bits (4 VGPRs)
typedef __attribute__((ext_vector_type(4))) float f32x4;
typedef __attribute__((ext_vector_type(16))) float f32x16;
typedef unsigned short ushort_t;

__device__ __forceinline__ unsigned short f2bf(float x) {
    unsigned int u = __builtin_bit_cast(unsigned int, x);
    unsigned int r = (u + 0x7fffu + ((u >> 16) & 1u)) >> 16;   // RNE
    return (unsigned short)r;
}

__device__ __forceinline__ void gload_lds16(const ushort_t* g, ushort_t* l) {
    __builtin_amdgcn_global_load_lds(
        (const __attribute__((address_space(1))) void*)g,
        (__attribute__((address_space(3))) void*)l, 16, 0, 0);
}

#define MFMA16(A, B, C) __builtin_amdgcn_mfma_f32_16x16x32_bf16((A), (B), (C), 0, 0, 0)
#define MFMA32(A, B, C) __builtin_amdgcn_mfma_f32_32x32x16_bf16((A), (B), (C), 0, 0, 0)

// ---------------- fused prep: fp32->bf16 convert (5 tensors) + sincos table ----------------
// blocks 0..14335: cvt segments; blocks 14336..15359: qh fill (8 elems/thread)
__global__ __launch_bounds__(256) void prep_all(const float* __restrict__ im,
                                                const float* __restrict__ iq,
                                                const float* __restrict__ ik,
                                                const float* __restrict__ iv,
                                                const float* __restrict__ io,
                                                ushort_t* __restrict__ om,
                                                ushort_t* __restrict__ oq,
                                                ushort_t* __restrict__ ok,
                                                ushort_t* __restrict__ ov,
                                                ushort_t* __restrict__ oo,
                                                ushort_t* __restrict__ qh) {
    const int bid = blockIdx.x;
    if (bid < 14336) {
        long i = ((long)bid * 256 + threadIdx.x) << 3;
        const float* s;
        ushort_t* d;
        if (i < 16777216)      { s = im + i;              d = om + i; }
        else if (i < 20971520) { s = iq + (i - 16777216); d = oq + (i - 16777216); }
        else if (i < 23068672) { s = ik + (i - 20971520); d = ok + (i - 20971520); }
        else if (i < 25165824) { s = iv + (i - 23068672); d = ov + (i - 23068672); }
        else                   { s = io + (i - 25165824); d = oo + (i - 25165824); }
        const float4* p = (const float4*)s;
        float4 a = p[0], b = p[1];
        short8 o;
        o[0] = (short)f2bf(a.x); o[1] = (short)f2bf(a.y);
        o[2] = (short)f2bf(a.z); o[3] = (short)f2bf(a.w);
        o[4] = (short)f2bf(b.x); o[5] = (short)f2bf(b.y);
        o[6] = (short)f2bf(b.z); o[7] = (short)f2bf(b.w);
        *(short8*)d = o;
    } else {
        // qh fill: 8 consecutive i per thread, vectorized short8 stores
        const int t8 = (bid - 14336) * 256 + threadIdx.x;   // over 2048*128
        const int e = t8 >> 7;
        const int i0 = (t8 & 127) << 3;
        short8 sv8, cv8;
#pragma unroll
        for (int j = 0; j < 8; ++j) {
            const int i = i0 + j;
            float freq = __expf(-9.2103403719761836f * (float)i * (1.0f / 1024.0f));
            float ang = (float)e * freq;
            float rev = ang * 0.15915494309189535f;
            rev -= floorf(rev);
            float sv, cv;
            asm("v_sin_f32 %0, %1" : "=v"(sv) : "v"(rev));
            asm("v_cos_f32 %0, %1" : "=v"(cv) : "v"(rev));
            sv8[j] = (short)f2bf(sv);
            cv8[j] = (short)f2bf(cv);
        }
        *(short8*)(qh + (size_t)e * 2048 + i0)        = sv8;
        *(short8*)(qh + (size_t)e * 2048 + 1024 + i0) = cv8;
    }
}

// ---------------- Q-proj GEMM: 128x128, BK=32, QUAD-buffer, counted vmcnt ----------
__global__ __launch_bounds__(256, 2) void gemm_q(const ushort_t* __restrict__ A,
                                                 const ushort_t* __restrict__ Bw,
                                                 const float* __restrict__ bias,
                                                 ushort_t* __restrict__ Cout,
                                                 int M, int N, int K) {
    __shared__ ushort_t As[4][128 * 32];
    __shared__ ushort_t Bs[4][128 * 32];
    const int tid = threadIdx.x, lane = tid & 63;
    const int wid = tid >> 6;
    const int q5 = lane & 31, hi = lane >> 5;
    const int wm = wid >> 1, wn = wid & 1;
    const int nbn = N >> 7;
    const int nwg = gridDim.x;
    const int swz = (blockIdx.x & 7) * (nwg >> 3) + (blockIdx.x >> 3);
    const int bm = swz / nbn, bn = swz % nbn;
    const int row0 = bm << 7, col0 = bn << 7;
    const int NT = K >> 5;

    f32x16 acc[2][2];
#pragma unroll
    for (int mi = 0; mi < 2; ++mi)
#pragma unroll
        for (int nj = 0; nj < 2; ++nj)
#pragma unroll
            for (int rr = 0; rr < 16; ++rr) acc[mi][nj][rr] = 0.f;

    auto STAGE_HALF = [&](int buf, int kt, int i) {
        const int k0 = kt << 5;
        const int fb = (i * 256 + tid) << 4;
        const int rp = fb >> 7;
        const int bo = ((fb >> 4) & 7) ^ (rp & 7);
        const int row = rp * 2 + (bo >> 2);
        const int kc = (bo & 3) << 3;
        gload_lds16(A  + (size_t)(row0 + row) * K + k0 + kc, &As[buf][0] + (fb >> 1));
        gload_lds16(Bw + (size_t)(col0 + row) * K + k0 + kc, &Bs[buf][0] + (fb >> 1));
    };

    STAGE_HALF(0, 0, 0); STAGE_HALF(0, 0, 1);
    STAGE_HALF(1, 1, 0); STAGE_HALF(1, 1, 1);
    STAGE_HALF(2, 2, 0); STAGE_HALF(2, 2, 1);
    asm volatile("s_waitcnt vmcnt(8)" ::: "memory");
    __builtin_amdgcn_sched_barrier(0);
    __builtin_amdgcn_s_barrier();
    __builtin_amdgcn_sched_barrier(0);

    for (int t = 0; t < NT; ++t) {
        const int buf = t & 3;
        const char* Ab = (const char*)&As[buf][0];
        const char* Bb = (const char*)&Bs[buf][0];
#pragma unroll
        for (int ph = 0; ph < 2; ++ph) {
            short8 af[2], bfr[2];
#pragma unroll
            for (int nj = 0; nj < 2; ++nj) {
                const int col = wn * 64 + nj * 32 + q5;
                const int rp = col >> 1;
                const int blk = (((col & 1) << 2) + ph * 2 + hi) ^ (rp & 7);
                bfr[nj] = *(const short8*)(Bb + rp * 128 + blk * 16);
            }
#pragma unroll
            for (int mi = 0; mi < 2; ++mi) {
                const int row = wm * 64 + mi * 32 + q5;
                const int rp = row >> 1;
                const int blk = (((row & 1) << 2) + ph * 2 + hi) ^ (rp & 7);
                af[mi] = *(const short8*)(Ab + rp * 128 + blk * 16);
            }
            if (t + 3 < NT) STAGE_HALF((t + 3) & 3, t + 3, ph);
            __builtin_amdgcn_s_setprio(1);
#pragma unroll
            for (int mi = 0; mi < 2; ++mi)
#pragma unroll
                for (int nj = 0; nj < 2; ++nj)
                    acc[mi][nj] = MFMA32(af[mi], bfr[nj], acc[mi][nj]);
            __builtin_amdgcn_s_setprio(0);
        }

        if (t + 3 < NT) {
            asm volatile("s_waitcnt vmcnt(8)" ::: "memory");
        } else if (t + 2 < NT) {
            asm volatile("s_waitcnt vmcnt(4)" ::: "memory");
        } else if (t + 1 < NT) {
            asm volatile("s_waitcnt vmcnt(0)" ::: "memory");
        }
        if (t + 1 < NT) {
            __builtin_amdgcn_sched_barrier(0);
            __builtin_amdgcn_s_barrier();
            __builtin_amdgcn_sched_barrier(0);
        }
    }

#pragma unroll
    for (int mi = 0; mi < 2; ++mi)
#pragma unroll
        for (int nj = 0; nj < 2; ++nj) {
            const int col = col0 + wn * 64 + nj * 32 + q5;
            const float bv = bias[col];
#pragma unroll
            for (int rr = 0; rr < 16; ++rr) {
                const int row = row0 + wm * 64 + mi * 32 + (rr & 3) + 8 * (rr >> 2) + 4 * hi;
                Cout[(size_t)row * N + col] = f2bf((acc[mi][nj][rr] + bv) * 0.5f);
            }
        }
}

// ---------------- 256x256 GEMM, BK=32, QUAD-buffer, counted vmcnt(8), phase-split ----
// (proven round-10 version, unchanged)
template <int EPI>
__global__ __launch_bounds__(512, 1) void gemm256(const ushort_t* __restrict__ A,
                                                  const ushort_t* __restrict__ Bw,
                                                  const float* __restrict__ b0,
                                                  const float* __restrict__ b1,
                                                  void* __restrict__ C0,
                                                  void* __restrict__ C1,
                                                  int M, int N, int K) {
    __shared__ ushort_t As[4][256 * 32];
    __shared__ ushort_t Bs[4][256 * 32];
    const int tid = threadIdx.x, lane = tid & 63;
    const int wid = tid >> 6;
    const int q5 = lane & 31, hi = lane >> 5;
    const int wm = wid >> 2, wn = wid & 3;
    const int nbn = N >> 8;
    const int nwg = gridDim.x;
    const int swz = (blockIdx.x & 7) * (nwg >> 3) + (blockIdx.x >> 3);
    const int bm = swz / nbn, bn = swz % nbn;
    const int row0 = bm << 8, col0 = bn << 8;
    const int NT = K >> 5;

    f32x16 acc[4][2];
#pragma unroll
    for (int mi = 0; mi < 4; ++mi)
#pragma unroll
        for (int nj = 0; nj < 2; ++nj)
#pragma unroll
            for (int rr = 0; rr < 16; ++rr) acc[mi][nj][rr] = 0.f;

    auto STAGE_HALF = [&](int buf, int kt, int i) {
        const int k0 = kt << 5;
        const int fb = (i * 512 + tid) << 4;
        const int rp = fb >> 7;
        const int bo = ((fb >> 4) & 7) ^ (rp & 7);
        const int row = rp * 2 + (bo >> 2);
        const int kc = (bo & 3) << 3;
        gload_lds16(A  + (size_t)(row0 + row) * K + k0 + kc, &As[buf][0] + (fb >> 1));
        gload_lds16(Bw + (size_t)(col0 + row) * K + k0 + kc, &Bs[buf][0] + (fb >> 1));
    };

    STAGE_HALF(0, 0, 0); STAGE_HALF(0, 0, 1);
    STAGE_HALF(1, 1, 0); STAGE_HALF(1, 1, 1);
    STAGE_HALF(2, 2, 0); STAGE_HALF(2, 2, 1);
    asm volatile("s_waitcnt vmcnt(8)" ::: "memory");
    __builtin_amdgcn_sched_barrier(0);
    __builtin_amdgcn_s_barrier();
    __builtin_amdgcn_sched_barrier(0);

    for (int t = 0; t < NT; ++t) {
        const int buf = t & 3;
        const char* Ab = (const char*)&As[buf][0];
        const char* Bb = (const char*)&Bs[buf][0];
#pragma unroll
        for (int ph = 0; ph < 2; ++ph) {
            short8 af[4], bfr[2];
#pragma unroll
            for (int nj = 0; nj < 2; ++nj) {
                const int col = wn * 64 + nj * 32 + q5;
                const int rp = col >> 1;
                const int blk = (((col & 1) << 2) + ph * 2 + hi) ^ (rp & 7);
                bfr[nj] = *(const short8*)(Bb + rp * 128 + blk * 16);
            }
#pragma unroll
            for (int mi = 0; mi < 4; ++mi) {
                const int row = wm * 128 + mi * 32 + q5;
                const int rp = row >> 1;
                const int blk = (((row & 1) << 2) + ph * 2 + hi) ^ (rp & 7);
                af[mi] = *(const short8*)(Ab + rp * 128 + blk * 16);
            }
            if (t + 3 < NT) STAGE_HALF((t + 3) & 3, t + 3, ph);
            __builtin_amdgcn_s_setprio(1);
#pragma unroll
            for (int mi = 0; mi < 4; ++mi)
#pragma unroll
                for (int nj = 0; nj < 2; ++nj)
                    acc[mi][nj] = MFMA32(af[mi], bfr[nj], acc[mi][nj]);
            __builtin_amdgcn_s_setprio(0);
        }

        if (t + 3 < NT) {
            asm volatile("s_waitcnt vmcnt(8)" ::: "memory");
        } else if (t + 2 < NT) {
            asm volatile("s_waitcnt vmcnt(4)" ::: "memory");
        } else if (t + 1 < NT) {
            asm volatile("s_waitcnt vmcnt(0)" ::: "memory");
        }
        if (t + 1 < NT) {
            __builtin_amdgcn_sched_barrier(0);
            __builtin_amdgcn_s_barrier();
            __builtin_amdgcn_sched_barrier(0);
        }
    }

#pragma unroll
    for (int mi = 0; mi < 4; ++mi)
#pragma unroll
        for (int nj = 0; nj < 2; ++nj) {
            const int col = col0 + wn * 64 + nj * 32 + q5;
            if (EPI == 2) {
                float* outp = (float*)C0;
#pragma unroll
                for (int rr = 0; rr < 16; ++rr) {
                    const int row = row0 + wm * 128 + mi * 32 + (rr & 3) + 8 * (rr >> 2) + 4 * hi;
                    outp[(size_t)row * N + col] = acc[mi][nj][rr];
                }
            } else {
                if (col < 1024) {
                    const float bv = b0[col];
                    ushort_t* Kp = (ushort_t*)C0;
#pragma unroll
                    for (int rr = 0; rr < 16; ++rr) {
                        const int row = row0 + wm * 128 + mi * 32 + (rr & 3) + 8 * (rr >> 2) + 4 * hi;
                        Kp[(size_t)row * 1024 + col] = f2bf(acc[mi][nj][rr] + bv);
                    }
                } else {
                    const int vcol = col - 1024;
                    const float bv = b1[vcol];
                    ushort_t* Vt = (ushort_t*)C1;
#pragma unroll
                    for (int G = 0; G < 4; ++G) {
                        const int m0 = row0 + wm * 128 + mi * 32 + G * 8 + 4 * hi;
                        const int bb = m0 >> 11;
                        const int mm = m0 & 2047;
                        const size_t vtrow = (size_t)(bb * 8 + (vcol >> 7)) * 128 + (vcol & 127);
                        unsigned int p0 = (unsigned int)f2bf(acc[mi][nj][G * 4 + 0] + bv)
                                        | ((unsigned int)f2bf(acc[mi][nj][G * 4 + 1] + bv) << 16);
                        unsigned int p1 = (unsigned int)f2bf(acc[mi][nj][G * 4 + 2] + bv)
                                        | ((unsigned int)f2bf(acc[mi][nj][G * 4 + 3] + bv) << 16);
                        uint2 pk; pk.x = p0; pk.y = p1;
                        *(uint2*)(Vt + vtrow * 2048 + mm) = pk;
                    }
                }
            }
        }
}

// ---------------- GQA flash attention v5 (proven round-8/11 version, reverted) ----------
// Q [2048, 16*128] (pre-scaled 0.5), K [8192, 1024] row-major,
// Vt [(b*8+kvh)*128+d][2048] transposed, O [4,2048,2048] bf16.
// Unnormalized softmax (bounded scores), precomputed LDS offsets, 2x-unrolled dbuf.
__global__ __launch_bounds__(512, 2) void attn_kernel(const ushort_t* __restrict__ Q,
                                                      const ushort_t* __restrict__ Kg,
                                                      const ushort_t* __restrict__ Vt,
                                                      ushort_t* __restrict__ O) {
    __shared__ ushort_t Ks[2][64 * 128];    // 16KB per buf
    __shared__ ushort_t Vts[2][128 * 64];   // 16KB per buf

    const int tid = threadIdx.x, lane = tid & 63, wid = tid >> 6;
    const int q5 = lane & 31;
    const int hi = lane >> 5;
    const int wq = wid & 3;
    const int wg = (blockIdx.x & 7) * 64 + (blockIdx.x >> 3);
    const int bkvh = wg >> 4;
    const int etile = wg & 15;
    const int b = bkvh >> 3, kvh = bkvh & 7;
    const int h = kvh * 2 + (wid >> 2);
    const int e0 = etile * 128;
    const int qrow = e0 + wq * 32 + q5;

    short8 Qf[8];
    {
        const ushort_t* qp = Q + (size_t)qrow * 2048 + h * 128 + hi * 8;
#pragma unroll
        for (int c = 0; c < 8; ++c) Qf[c] = *(const short8*)(qp + c * 16);
    }

    unsigned aK[2][8];
#pragma unroll
    for (int h2 = 0; h2 < 2; ++h2) {
        const int key = h2 * 32 + q5;
#pragma unroll
        for (int c = 0; c < 8; ++c)
            aK[h2][c] = key * 256 + (((c * 2 + hi) ^ (key & 7)) << 4);
    }
    unsigned aV[4];
#pragma unroll
    for (int c16 = 0; c16 < 4; ++c16)
        aV[c16] = q5 * 128 + (((c16 * 2 + hi) ^ (q5 & 7)) << 4);

    float lrow = 0.f;
    f32x16 oacc[4];
#pragma unroll
    for (int d0 = 0; d0 < 4; ++d0)
#pragma unroll
        for (int r = 0; r < 16; ++r) oacc[d0][r] = 0.f;

    f32x16 Z16;
#pragma unroll
    for (int r = 0; r < 16; ++r) Z16[r] = 0.f;

    const ushort_t* Kbase  = Kg + (size_t)b * 2048 * 1024 + kvh * 128;
    const ushort_t* Vtbase = Vt + (size_t)bkvh * 128 * 2048;

    auto STAGE = [&](int buf, int kv0) {
#pragma unroll
        for (int i = 0; i < 2; ++i) {
            const int fb = (i * 8 + wid) * 1024 + lane * 16;
            const int key = fb >> 8;
            const int blk = (fb >> 4) & 15;
            gload_lds16(Kbase + (size_t)(kv0 + key) * 1024 + ((blk ^ (key & 7)) << 3),
                        &Ks[buf][0] + (fb >> 1));
            const int d = fb >> 7;
            const int kb = (fb >> 4) & 7;
            gload_lds16(Vtbase + (size_t)d * 2048 + kv0 + ((kb ^ (d & 7)) << 3),
                        &Vts[buf][0] + (fb >> 1));
        }
    };

    auto TILE = [&](int bo) {    // bo: 0 or 16384 (compile-time at call sites)
        f32x16 sS[2];
        __builtin_amdgcn_s_setprio(1);
#pragma unroll
        for (int c = 0; c < 8; ++c) {
            short8 ka0 = *(const short8*)((const char*)Ks + bo + aK[0][c]);
            short8 ka1 = *(const short8*)((const char*)Ks + bo + aK[1][c]);
            sS[0] = MFMA32(ka0, Qf[c], (c == 0) ? Z16 : sS[0]);
            sS[1] = MFMA32(ka1, Qf[c], (c == 0) ? Z16 : sS[1]);
        }
        __builtin_amdgcn_s_setprio(0);

#pragma unroll
        for (int h2 = 0; h2 < 2; ++h2)
#pragma unroll
            for (int r = 0; r < 16; ++r) sS[h2][r] = __expf(sS[h2][r]);

        float ts[16];
#pragma unroll
        for (int i = 0; i < 8; ++i) ts[i] = sS[0][2 * i] + sS[0][2 * i + 1];
#pragma unroll
        for (int i = 0; i < 8; ++i) ts[8 + i] = sS[1][2 * i] + sS[1][2 * i + 1];
#pragma unroll
        for (int s = 8; s > 0; s >>= 1)
#pragma unroll
            for (int i = 0; i < s; ++i) ts[i] += ts[i + s];
        lrow += ts[0] + __shfl_xor(ts[0], 32);

        unsigned int W[2][4][2];
#pragma unroll
        for (int h2 = 0; h2 < 2; ++h2)
#pragma unroll
            for (int q4 = 0; q4 < 4; ++q4)
#pragma unroll
                for (int p = 0; p < 2; ++p) {
                    unsigned int w;
                    asm("v_cvt_pk_bf16_f32 %0, %1, %2"
                        : "=v"(w)
                        : "v"(sS[h2][q4 * 4 + 2 * p]), "v"(sS[h2][q4 * 4 + 2 * p + 1]));
                    W[h2][q4][p] = w;
                }

#pragma unroll
        for (int c16 = 0; c16 < 4; ++c16) {
            const int h2 = c16 >> 1;
            const int q4a = (c16 & 1) * 2, q4b = q4a + 1;
            auto r0 = __builtin_amdgcn_permlane32_swap(W[h2][q4a][0], W[h2][q4b][0], false, false);
            auto r1 = __builtin_amdgcn_permlane32_swap(W[h2][q4a][1], W[h2][q4b][1], false, false);
            union { unsigned int w[4]; short8 v; } pa;
            pa.w[0] = r0[0];
            pa.w[1] = r1[0];
            pa.w[2] = r0[1];
            pa.w[3] = r1[1];
            __builtin_amdgcn_s_setprio(1);
#pragma unroll
            for (int d0 = 0; d0 < 4; ++d0) {
                short8 vb = *(const short8*)((const char*)Vts + bo + aV[c16] + d0 * 4096);
                oacc[d0] = MFMA32(pa.v, vb, oacc[d0]);
            }
            __builtin_amdgcn_s_setprio(0);
        }
    };

    STAGE(0, 0);
    __syncthreads();

#pragma unroll 1
    for (int tt = 0; tt < 16; ++tt) {
        STAGE(1, (2 * tt + 1) * 64);      // prefetch odd tile -> buf1
        TILE(0);                          // compute even tile from buf0
        __syncthreads();
        if (tt < 15) STAGE(0, (2 * tt + 2) * 64);  // prefetch next even -> buf0
        TILE(16384);                      // compute odd tile from buf1
        __syncthreads();
    }

#pragma unroll
    for (int reg = 0; reg < 16; ++reg) {
        const int qr = (reg & 3) + 8 * (reg >> 2) + 4 * hi;
        const float lr = __shfl(lrow, qr);
        const float inv = 1.0f / lr;
        const int e = e0 + wq * 32 + qr;
        ushort_t* op = O + ((size_t)b * 2048 + e) * 2048 + h * 128 + q5;
#pragma unroll
        for (int d0 = 0; d0 < 4; ++d0)
            op[d0 * 32] = f2bf(oacc[d0][reg] * inv);
    }
}

// ---------------- launch ----------------
extern "C" void kernel_launch(void* const* d_in, const int* in_sizes, int n_in,
                              void* d_out, int out_size, void* d_ws, size_t ws_size,
                              hipStream_t stream) {
    const float* mem_act = (const float*)d_in[0];
    const float* Wq = (const float*)d_in[1];
    const float* bq = (const float*)d_in[2];
    const float* Wk = (const float*)d_in[3];
    const float* bk = (const float*)d_in[4];
    const float* Wv = (const float*)d_in[5];
    const float* bv = (const float*)d_in[6];
    const float* Wo = (const float*)d_in[7];
    float* out = (float*)d_out;

    char* w = (char*)d_ws;
    ushort_t* memb = (ushort_t*)w; w += (size_t)16777216 * 2;  // [8192, 2048]
    ushort_t* wqb  = (ushort_t*)w; w += (size_t)4194304 * 2;   // [2048, 2048]
    ushort_t* wkvb = (ushort_t*)w; w += (size_t)4194304 * 2;   // [2048, 2048] = Wk | Wv
    ushort_t* wob  = (ushort_t*)w; w += (size_t)4194304 * 2;   // [2048, 2048]
    ushort_t* qh   = (ushort_t*)w; w += (size_t)4194304 * 2;   // [2048, 2048]
    ushort_t* Qp   = (ushort_t*)w; w += (size_t)4194304 * 2;   // [2048, 2048] (scaled by 0.5)
    ushort_t* Kp   = (ushort_t*)w; w += (size_t)8388608 * 2;   // [8192, 1024]
    ushort_t* Vtp  = (ushort_t*)w; w += (size_t)8388608 * 2;   // [4096, 2048] transposed V
    ushort_t* AO   = (ushort_t*)w; w += (size_t)16777216 * 2;  // [8192, 2048]

    dim3 blk(256);
    prep_all<<<15360, blk, 0, stream>>>(mem_act, Wq, Wk, Wv, Wo,
                                        memb, wqb, wkvb, wkvb + (size_t)2097152, wob, qh);

    gemm_q<<<16 * 16, blk, 0, stream>>>(qh, wqb, bq, Qp, 2048, 2048, 2048);

    // merged K+V projection: N=2048 (cols 0-1023 -> K, 1024-2047 -> V transposed)
    gemm256<0><<<256, dim3(512), 0, stream>>>(memb, wkvb, bk, bv, Kp, Vtp, 8192, 2048, 2048);

    attn_kernel<<<512, dim3(512), 0, stream>>>(Qp, Kp, Vtp, AO);

    gemm256<2><<<256, dim3(512), 0, stream>>>(AO, wob, nullptr, nullptr, out, nullptr, 8192, 2048, 2048);
}

// Round 14
// 357.844 us; speedup vs baseline: 1.6423x; 1.0168x over previous
//
#include <hip/hip_runtime.h>
#include <hip/hip_bf16.h>

// ---------------- common types / helpers ----------------
typedef __attribute__((ext_vector_type(8))) short short8;   // 8 x bf16 bits (4 VGPRs)
typedef __attribute__((ext_vector_type(4))) float f32x4;
typedef __attribute__((ext_vector_type(16))) float f32x16;
typedef unsigned short ushort_t;

__device__ __forceinline__ unsigned short f2bf(float x) {
    unsigned int u = __builtin_bit_cast(unsigned int, x);
    unsigned int r = (u + 0x7fffu + ((u >> 16) & 1u)) >> 16;   // RNE
    return (unsigned short)r;
}

__device__ __forceinline__ void gload_lds16(const ushort_t* g, ushort_t* l) {
    __builtin_amdgcn_global_load_lds(
        (const __attribute__((address_space(1))) void*)g,
        (__attribute__((address_space(3))) void*)l, 16, 0, 0);
}

#define MFMA16(A, B, C) __builtin_amdgcn_mfma_f32_16x16x32_bf16((A), (B), (C), 0, 0, 0)
#define MFMA32(A, B, C) __builtin_amdgcn_mfma_f32_32x32x16_bf16((A), (B), (C), 0, 0, 0)

// ---------------- fused prep: fp32->bf16 convert (5 tensors) + sincos table ----------------
// blocks 0..14335: cvt segments; blocks 14336..15359: qh fill (8 elems/thread)
__global__ __launch_bounds__(256) void prep_all(const float* __restrict__ im,
                                                const float* __restrict__ iq,
                                                const float* __restrict__ ik,
                                                const float* __restrict__ iv,
                                                const float* __restrict__ io,
                                                ushort_t* __restrict__ om,
                                                ushort_t* __restrict__ oq,
                                                ushort_t* __restrict__ ok,
                                                ushort_t* __restrict__ ov,
                                                ushort_t* __restrict__ oo,
                                                ushort_t* __restrict__ qh) {
    const int bid = blockIdx.x;
    if (bid < 14336) {
        long i = ((long)bid * 256 + threadIdx.x) << 3;
        const float* s;
        ushort_t* d;
        if (i < 16777216)      { s = im + i;              d = om + i; }
        else if (i < 20971520) { s = iq + (i - 16777216); d = oq + (i - 16777216); }
        else if (i < 23068672) { s = ik + (i - 20971520); d = ok + (i - 20971520); }
        else if (i < 25165824) { s = iv + (i - 23068672); d = ov + (i - 23068672); }
        else                   { s = io + (i - 25165824); d = oo + (i - 25165824); }
        const float4* p = (const float4*)s;
        float4 a = p[0], b = p[1];
        short8 o;
        o[0] = (short)f2bf(a.x); o[1] = (short)f2bf(a.y);
        o[2] = (short)f2bf(a.z); o[3] = (short)f2bf(a.w);
        o[4] = (short)f2bf(b.x); o[5] = (short)f2bf(b.y);
        o[6] = (short)f2bf(b.z); o[7] = (short)f2bf(b.w);
        *(short8*)d = o;
    } else {
        // qh fill: 8 consecutive i per thread, vectorized short8 stores
        const int t8 = (bid - 14336) * 256 + threadIdx.x;   // over 2048*128
        const int e = t8 >> 7;
        const int i0 = (t8 & 127) << 3;
        short8 sv8, cv8;
#pragma unroll
        for (int j = 0; j < 8; ++j) {
            const int i = i0 + j;
            float freq = __expf(-9.2103403719761836f * (float)i * (1.0f / 1024.0f));
            float ang = (float)e * freq;
            float rev = ang * 0.15915494309189535f;
            rev -= floorf(rev);
            float sv, cv;
            asm("v_sin_f32 %0, %1" : "=v"(sv) : "v"(rev));
            asm("v_cos_f32 %0, %1" : "=v"(cv) : "v"(rev));
            sv8[j] = (short)f2bf(sv);
            cv8[j] = (short)f2bf(cv);
        }
        *(short8*)(qh + (size_t)e * 2048 + i0)        = sv8;
        *(short8*)(qh + (size_t)e * 2048 + 1024 + i0) = cv8;
    }
}

// ---------------- Q-proj GEMM: 128x128, BK=32, QUAD-buffer, counted vmcnt ----------
// (proven round-11 version, unchanged)
__global__ __launch_bounds__(256, 2) void gemm_q(const ushort_t* __restrict__ A,
                                                 const ushort_t* __restrict__ Bw,
                                                 const float* __restrict__ bias,
                                                 ushort_t* __restrict__ Cout,
                                                 int M, int N, int K) {
    __shared__ ushort_t As[4][128 * 32];
    __shared__ ushort_t Bs[4][128 * 32];
    const int tid = threadIdx.x, lane = tid & 63;
    const int wid = tid >> 6;
    const int q5 = lane & 31, hi = lane >> 5;
    const int wm = wid >> 1, wn = wid & 1;
    const int nbn = N >> 7;
    const int nwg = gridDim.x;
    const int swz = (blockIdx.x & 7) * (nwg >> 3) + (blockIdx.x >> 3);
    const int bm = swz / nbn, bn = swz % nbn;
    const int row0 = bm << 7, col0 = bn << 7;
    const int NT = K >> 5;

    f32x16 acc[2][2];
#pragma unroll
    for (int mi = 0; mi < 2; ++mi)
#pragma unroll
        for (int nj = 0; nj < 2; ++nj)
#pragma unroll
            for (int rr = 0; rr < 16; ++rr) acc[mi][nj][rr] = 0.f;

    auto STAGE_HALF = [&](int buf, int kt, int i) {
        const int k0 = kt << 5;
        const int fb = (i * 256 + tid) << 4;
        const int rp = fb >> 7;
        const int bo = ((fb >> 4) & 7) ^ (rp & 7);
        const int row = rp * 2 + (bo >> 2);
        const int kc = (bo & 3) << 3;
        gload_lds16(A  + (size_t)(row0 + row) * K + k0 + kc, &As[buf][0] + (fb >> 1));
        gload_lds16(Bw + (size_t)(col0 + row) * K + k0 + kc, &Bs[buf][0] + (fb >> 1));
    };

    STAGE_HALF(0, 0, 0); STAGE_HALF(0, 0, 1);
    STAGE_HALF(1, 1, 0); STAGE_HALF(1, 1, 1);
    STAGE_HALF(2, 2, 0); STAGE_HALF(2, 2, 1);
    asm volatile("s_waitcnt vmcnt(8)" ::: "memory");
    __builtin_amdgcn_sched_barrier(0);
    __builtin_amdgcn_s_barrier();
    __builtin_amdgcn_sched_barrier(0);

    for (int t = 0; t < NT; ++t) {
        const int buf = t & 3;
        const char* Ab = (const char*)&As[buf][0];
        const char* Bb = (const char*)&Bs[buf][0];
#pragma unroll
        for (int ph = 0; ph < 2; ++ph) {
            short8 af[2], bfr[2];
#pragma unroll
            for (int nj = 0; nj < 2; ++nj) {
                const int col = wn * 64 + nj * 32 + q5;
                const int rp = col >> 1;
                const int blk = (((col & 1) << 2) + ph * 2 + hi) ^ (rp & 7);
                bfr[nj] = *(const short8*)(Bb + rp * 128 + blk * 16);
            }
#pragma unroll
            for (int mi = 0; mi < 2; ++mi) {
                const int row = wm * 64 + mi * 32 + q5;
                const int rp = row >> 1;
                const int blk = (((row & 1) << 2) + ph * 2 + hi) ^ (rp & 7);
                af[mi] = *(const short8*)(Ab + rp * 128 + blk * 16);
            }
            if (t + 3 < NT) STAGE_HALF((t + 3) & 3, t + 3, ph);
            __builtin_amdgcn_s_setprio(1);
#pragma unroll
            for (int mi = 0; mi < 2; ++mi)
#pragma unroll
                for (int nj = 0; nj < 2; ++nj)
                    acc[mi][nj] = MFMA32(af[mi], bfr[nj], acc[mi][nj]);
            __builtin_amdgcn_s_setprio(0);
        }

        if (t + 3 < NT) {
            asm volatile("s_waitcnt vmcnt(8)" ::: "memory");
        } else if (t + 2 < NT) {
            asm volatile("s_waitcnt vmcnt(4)" ::: "memory");
        } else if (t + 1 < NT) {
            asm volatile("s_waitcnt vmcnt(0)" ::: "memory");
        }
        if (t + 1 < NT) {
            __builtin_amdgcn_sched_barrier(0);
            __builtin_amdgcn_s_barrier();
            __builtin_amdgcn_sched_barrier(0);
        }
    }

#pragma unroll
    for (int mi = 0; mi < 2; ++mi)
#pragma unroll
        for (int nj = 0; nj < 2; ++nj) {
            const int col = col0 + wn * 64 + nj * 32 + q5;
            const float bv = bias[col];
#pragma unroll
            for (int rr = 0; rr < 16; ++rr) {
                const int row = row0 + wm * 64 + mi * 32 + (rr & 3) + 8 * (rr >> 2) + 4 * hi;
                Cout[(size_t)row * N + col] = f2bf((acc[mi][nj][rr] + bv) * 0.5f);
            }
        }
}

// ---------------- 256x256 GEMM, BK=64, DOUBLE-buffer, front-loaded staging ----------
// C[M,N] = A[M,K] * Bw[N,K]^T. 8 waves (2m x 4n), per-wave 128x64.
// 2 bufs x (32KB A + 32KB B) = 128KB LDS. All 8 staging loads for tile t+1 issue at
// the top of tile t (~2000cyc before the end-of-tile vmcnt(0) -> drain is free).
// Half the barrier/vmcnt events of the BK=32 quad version.
// LDS layout: 128B rows (64 k x 2B), 8 x 16B blocks, blk ^= (row&7)  [attn-proven].
// EPI 0: merged K/V epilogue; EPI 2: f32 out, no bias (O-proj).
template <int EPI>
__global__ __launch_bounds__(512, 1) void gemm256(const ushort_t* __restrict__ A,
                                                  const ushort_t* __restrict__ Bw,
                                                  const float* __restrict__ b0,
                                                  const float* __restrict__ b1,
                                                  void* __restrict__ C0,
                                                  void* __restrict__ C1,
                                                  int M, int N, int K) {
    __shared__ ushort_t As[2][256 * 64];   // 32KB per buf
    __shared__ ushort_t Bs[2][256 * 64];   // 32KB per buf  (total 128KB)
    const int tid = threadIdx.x, lane = tid & 63;
    const int wid = tid >> 6;
    const int q5 = lane & 31, hi = lane >> 5;
    const int wm = wid >> 2, wn = wid & 3;         // 2 x 4 waves
    const int nbn = N >> 8;
    const int nwg = gridDim.x;
    const int swz = (blockIdx.x & 7) * (nwg >> 3) + (blockIdx.x >> 3);   // XCD swizzle
    const int bm = swz / nbn, bn = swz % nbn;
    const int row0 = bm << 8, col0 = bn << 8;
    const int NT = K >> 6;                          // BK = 64

    f32x16 acc[4][2];
#pragma unroll
    for (int mi = 0; mi < 4; ++mi)
#pragma unroll
        for (int nj = 0; nj < 2; ++nj)
#pragma unroll
            for (int rr = 0; rr < 16; ++rr) acc[mi][nj][rr] = 0.f;

    // stage one full 256x64 K-tile of A and B into buf; 4+4 loads/thread.
    // LDS: row r at bytes [r*128, r*128+128), block b (16B) XOR-swizzled by (r&7);
    // swizzle applied on the global SOURCE k-offset, LDS dest stays linear.
    auto STAGE = [&](int buf, int kt) {
        const int k0 = kt << 6;
#pragma unroll
        for (int i = 0; i < 4; ++i) {
            const int fb = (i * 512 + tid) << 4;        // byte offset in 32KB tile
            const int row = fb >> 7;
            const int blk = (fb >> 4) & 7;
            const int kc = ((blk ^ (row & 7)) << 3);    // source k-elem offset
            gload_lds16(A  + (size_t)(row0 + row) * K + k0 + kc, &As[buf][0] + (fb >> 1));
            gload_lds16(Bw + (size_t)(col0 + row) * K + k0 + kc, &Bs[buf][0] + (fb >> 1));
        }
    };

    STAGE(0, 0);
    asm volatile("s_waitcnt vmcnt(0)" ::: "memory");
    __builtin_amdgcn_sched_barrier(0);
    __builtin_amdgcn_s_barrier();
    __builtin_amdgcn_sched_barrier(0);

    for (int t = 0; t < NT; ++t) {
        const int buf = t & 1;
        const char* Ab = (const char*)&As[buf][0];
        const char* Bb = (const char*)&Bs[buf][0];
        if (t + 1 < NT) STAGE(buf ^ 1, t + 1);     // front-load all 8 loads for t+1
#pragma unroll
        for (int kk = 0; kk < 4; ++kk) {           // 4 k16 phases
            short8 af[4], bfr[2];
#pragma unroll
            for (int nj = 0; nj < 2; ++nj) {
                const int col = wn * 64 + nj * 32 + q5;
                const int blk = (kk * 2 + hi) ^ (col & 7);
                bfr[nj] = *(const short8*)(Bb + col * 128 + blk * 16);
            }
#pragma unroll
            for (int mi = 0; mi < 4; ++mi) {
                const int row = wm * 128 + mi * 32 + q5;
                const int blk = (kk * 2 + hi) ^ (row & 7);
                af[mi] = *(const short8*)(Ab + row * 128 + blk * 16);
            }
            __builtin_amdgcn_s_setprio(1);
#pragma unroll
            for (int mi = 0; mi < 4; ++mi)
#pragma unroll
                for (int nj = 0; nj < 2; ++nj)
                    acc[mi][nj] = MFMA32(af[mi], bfr[nj], acc[mi][nj]);
            __builtin_amdgcn_s_setprio(0);
        }

        if (t + 1 < NT) {
            asm volatile("s_waitcnt vmcnt(0)" ::: "memory");   // t+1 staged ~2000cyc ago
            __builtin_amdgcn_sched_barrier(0);
            __builtin_amdgcn_s_barrier();
            __builtin_amdgcn_sched_barrier(0);
        }
    }

    // ---- epilogue ----
#pragma unroll
    for (int mi = 0; mi < 4; ++mi)
#pragma unroll
        for (int nj = 0; nj < 2; ++nj) {
            const int col = col0 + wn * 64 + nj * 32 + q5;
            if (EPI == 2) {
                float* outp = (float*)C0;
#pragma unroll
                for (int rr = 0; rr < 16; ++rr) {
                    const int row = row0 + wm * 128 + mi * 32 + (rr & 3) + 8 * (rr >> 2) + 4 * hi;
                    outp[(size_t)row * N + col] = acc[mi][nj][rr];
                }
            } else {
                if (col < 1024) {
                    const float bv = b0[col];
                    ushort_t* Kp = (ushort_t*)C0;
#pragma unroll
                    for (int rr = 0; rr < 16; ++rr) {
                        const int row = row0 + wm * 128 + mi * 32 + (rr & 3) + 8 * (rr >> 2) + 4 * hi;
                        Kp[(size_t)row * 1024 + col] = f2bf(acc[mi][nj][rr] + bv);
                    }
                } else {
                    const int vcol = col - 1024;
                    const float bv = b1[vcol];
                    ushort_t* Vt = (ushort_t*)C1;
#pragma unroll
                    for (int G = 0; G < 4; ++G) {
                        const int m0 = row0 + wm * 128 + mi * 32 + G * 8 + 4 * hi;
                        const int bb = m0 >> 11;
                        const int mm = m0 & 2047;
                        const size_t vtrow = (size_t)(bb * 8 + (vcol >> 7)) * 128 + (vcol & 127);
                        unsigned int p0 = (unsigned int)f2bf(acc[mi][nj][G * 4 + 0] + bv)
                                        | ((unsigned int)f2bf(acc[mi][nj][G * 4 + 1] + bv) << 16);
                        unsigned int p1 = (unsigned int)f2bf(acc[mi][nj][G * 4 + 2] + bv)
                                        | ((unsigned int)f2bf(acc[mi][nj][G * 4 + 3] + bv) << 16);
                        uint2 pk; pk.x = p0; pk.y = p1;
                        *(uint2*)(Vt + vtrow * 2048 + mm) = pk;
                    }
                }
            }
        }
}

// ---------------- GQA flash attention v5 (proven round-8/11 version, unchanged) ----------
__global__ __launch_bounds__(512, 2) void attn_kernel(const ushort_t* __restrict__ Q,
                                                      const ushort_t* __restrict__ Kg,
                                                      const ushort_t* __restrict__ Vt,
                                                      ushort_t* __restrict__ O) {
    __shared__ ushort_t Ks[2][64 * 128];    // 16KB per buf
    __shared__ ushort_t Vts[2][128 * 64];   // 16KB per buf

    const int tid = threadIdx.x, lane = tid & 63, wid = tid >> 6;
    const int q5 = lane & 31;
    const int hi = lane >> 5;
    const int wq = wid & 3;
    const int wg = (blockIdx.x & 7) * 64 + (blockIdx.x >> 3);
    const int bkvh = wg >> 4;
    const int etile = wg & 15;
    const int b = bkvh >> 3, kvh = bkvh & 7;
    const int h = kvh * 2 + (wid >> 2);
    const int e0 = etile * 128;
    const int qrow = e0 + wq * 32 + q5;

    short8 Qf[8];
    {
        const ushort_t* qp = Q + (size_t)qrow * 2048 + h * 128 + hi * 8;
#pragma unroll
        for (int c = 0; c < 8; ++c) Qf[c] = *(const short8*)(qp + c * 16);
    }

    unsigned aK[2][8];
#pragma unroll
    for (int h2 = 0; h2 < 2; ++h2) {
        const int key = h2 * 32 + q5;
#pragma unroll
        for (int c = 0; c < 8; ++c)
            aK[h2][c] = key * 256 + (((c * 2 + hi) ^ (key & 7)) << 4);
    }
    unsigned aV[4];
#pragma unroll
    for (int c16 = 0; c16 < 4; ++c16)
        aV[c16] = q5 * 128 + (((c16 * 2 + hi) ^ (q5 & 7)) << 4);

    float lrow = 0.f;
    f32x16 oacc[4];
#pragma unroll
    for (int d0 = 0; d0 < 4; ++d0)
#pragma unroll
        for (int r = 0; r < 16; ++r) oacc[d0][r] = 0.f;

    f32x16 Z16;
#pragma unroll
    for (int r = 0; r < 16; ++r) Z16[r] = 0.f;

    const ushort_t* Kbase  = Kg + (size_t)b * 2048 * 1024 + kvh * 128;
    const ushort_t* Vtbase = Vt + (size_t)bkvh * 128 * 2048;

    auto STAGE = [&](int buf, int kv0) {
#pragma unroll
        for (int i = 0; i < 2; ++i) {
            const int fb = (i * 8 + wid) * 1024 + lane * 16;
            const int key = fb >> 8;
            const int blk = (fb >> 4) & 15;
            gload_lds16(Kbase + (size_t)(kv0 + key) * 1024 + ((blk ^ (key & 7)) << 3),
                        &Ks[buf][0] + (fb >> 1));
            const int d = fb >> 7;
            const int kb = (fb >> 4) & 7;
            gload_lds16(Vtbase + (size_t)d * 2048 + kv0 + ((kb ^ (d & 7)) << 3),
                        &Vts[buf][0] + (fb >> 1));
        }
    };

    auto TILE = [&](int bo) {    // bo: 0 or 16384 (compile-time at call sites)
        f32x16 sS[2];
        __builtin_amdgcn_s_setprio(1);
#pragma unroll
        for (int c = 0; c < 8; ++c) {
            short8 ka0 = *(const short8*)((const char*)Ks + bo + aK[0][c]);
            short8 ka1 = *(const short8*)((const char*)Ks + bo + aK[1][c]);
            sS[0] = MFMA32(ka0, Qf[c], (c == 0) ? Z16 : sS[0]);
            sS[1] = MFMA32(ka1, Qf[c], (c == 0) ? Z16 : sS[1]);
        }
        __builtin_amdgcn_s_setprio(0);

#pragma unroll
        for (int h2 = 0; h2 < 2; ++h2)
#pragma unroll
            for (int r = 0; r < 16; ++r) sS[h2][r] = __expf(sS[h2][r]);

        float ts[16];
#pragma unroll
        for (int i = 0; i < 8; ++i) ts[i] = sS[0][2 * i] + sS[0][2 * i + 1];
#pragma unroll
        for (int i = 0; i < 8; ++i) ts[8 + i] = sS[1][2 * i] + sS[1][2 * i + 1];
#pragma unroll
        for (int s = 8; s > 0; s >>= 1)
#pragma unroll
            for (int i = 0; i < s; ++i) ts[i] += ts[i + s];
        lrow += ts[0] + __shfl_xor(ts[0], 32);

        unsigned int W[2][4][2];
#pragma unroll
        for (int h2 = 0; h2 < 2; ++h2)
#pragma unroll
            for (int q4 = 0; q4 < 4; ++q4)
#pragma unroll
                for (int p = 0; p < 2; ++p) {
                    unsigned int w;
                    asm("v_cvt_pk_bf16_f32 %0, %1, %2"
                        : "=v"(w)
                        : "v"(sS[h2][q4 * 4 + 2 * p]), "v"(sS[h2][q4 * 4 + 2 * p + 1]));
                    W[h2][q4][p] = w;
                }

#pragma unroll
        for (int c16 = 0; c16 < 4; ++c16) {
            const int h2 = c16 >> 1;
            const int q4a = (c16 & 1) * 2, q4b = q4a + 1;
            auto r0 = __builtin_amdgcn_permlane32_swap(W[h2][q4a][0], W[h2][q4b][0], false, false);
            auto r1 = __builtin_amdgcn_permlane32_swap(W[h2][q4a][1], W[h2][q4b][1], false, false);
            union { unsigned int w[4]; short8 v; } pa;
            pa.w[0] = r0[0];
            pa.w[1] = r1[0];
            pa.w[2] = r0[1];
            pa.w[3] = r1[1];
            __builtin_amdgcn_s_setprio(1);
#pragma unroll
            for (int d0 = 0; d0 < 4; ++d0) {
                short8 vb = *(const short8*)((const char*)Vts + bo + aV[c16] + d0 * 4096);
                oacc[d0] = MFMA32(pa.v, vb, oacc[d0]);
            }
            __builtin_amdgcn_s_setprio(0);
        }
    };

    STAGE(0, 0);
    __syncthreads();

#pragma unroll 1
    for (int tt = 0; tt < 16; ++tt) {
        STAGE(1, (2 * tt + 1) * 64);      // prefetch odd tile -> buf1
        TILE(0);                          // compute even tile from buf0
        __syncthreads();
        if (tt < 15) STAGE(0, (2 * tt + 2) * 64);  // prefetch next even -> buf0
        TILE(16384);                      // compute odd tile from buf1
        __syncthreads();
    }

#pragma unroll
    for (int reg = 0; reg < 16; ++reg) {
        const int qr = (reg & 3) + 8 * (reg >> 2) + 4 * hi;
        const float lr = __shfl(lrow, qr);
        const float inv = 1.0f / lr;
        const int e = e0 + wq * 32 + qr;
        ushort_t* op = O + ((size_t)b * 2048 + e) * 2048 + h * 128 + q5;
#pragma unroll
        for (int d0 = 0; d0 < 4; ++d0)
            op[d0 * 32] = f2bf(oacc[d0][reg] * inv);
    }
}

// ---------------- launch ----------------
extern "C" void kernel_launch(void* const* d_in, const int* in_sizes, int n_in,
                              void* d_out, int out_size, void* d_ws, size_t ws_size,
                              hipStream_t stream) {
    const float* mem_act = (const float*)d_in[0];
    const float* Wq = (const float*)d_in[1];
    const float* bq = (const float*)d_in[2];
    const float* Wk = (const float*)d_in[3];
    const float* bk = (const float*)d_in[4];
    const float* Wv = (const float*)d_in[5];
    const float* bv = (const float*)d_in[6];
    const float* Wo = (const float*)d_in[7];
    float* out = (float*)d_out;

    char* w = (char*)d_ws;
    ushort_t* memb = (ushort_t*)w; w += (size_t)16777216 * 2;  // [8192, 2048]
    ushort_t* wqb  = (ushort_t*)w; w += (size_t)4194304 * 2;   // [2048, 2048]
    ushort_t* wkvb = (ushort_t*)w; w += (size_t)4194304 * 2;   // [2048, 2048] = Wk | Wv
    ushort_t* wob  = (ushort_t*)w; w += (size_t)4194304 * 2;   // [2048, 2048]
    ushort_t* qh   = (ushort_t*)w; w += (size_t)4194304 * 2;   // [2048, 2048]
    ushort_t* Qp   = (ushort_t*)w; w += (size_t)4194304 * 2;   // [2048, 2048] (scaled by 0.5)
    ushort_t* Kp   = (ushort_t*)w; w += (size_t)8388608 * 2;   // [8192, 1024]
    ushort_t* Vtp  = (ushort_t*)w; w += (size_t)8388608 * 2;   // [4096, 2048] transposed V
    ushort_t* AO   = (ushort_t*)w; w += (size_t)16777216 * 2;  // [8192, 2048]

    dim3 blk(256);
    prep_all<<<15360, blk, 0, stream>>>(mem_act, Wq, Wk, Wv, Wo,
                                        memb, wqb, wkvb, wkvb + (size_t)2097152, wob, qh);

    gemm_q<<<16 * 16, blk, 0, stream>>>(qh, wqb, bq, Qp, 2048, 2048, 2048);

    // merged K+V projection: N=2048 (cols 0-1023 -> K, 1024-2047 -> V transposed)
    gemm256<0><<<256, dim3(512), 0, stream>>>(memb, wkvb, bk, bv, Kp, Vtp, 8192, 2048, 2048);

    attn_kernel<<<512, dim3(512), 0, stream>>>(Qp, Kp, Vtp, AO);

    gemm256<2><<<256, dim3(512), 0, stream>>>(AO, wob, nullptr, nullptr, out, nullptr, 8192, 2048, 2048);
}